// Round 8
// baseline (942.378 us; speedup 1.0000x reference)
//
#include <hip/hip_runtime.h>
#include <hip/hip_bf16.h>
#include <cstdint>

constexpr int NB = 256;   // batch
constexpr int NT = 512;   // frames
constexpr int ND = 512;   // dim

typedef __attribute__((ext_vector_type(8))) short bf16x8;
typedef __attribute__((ext_vector_type(4))) float f32x4;
typedef __attribute__((ext_vector_type(4))) unsigned int u32x4;
typedef __attribute__((ext_vector_type(2))) unsigned int u32x2;

__device__ __forceinline__ float wred_sum(float v){
#pragma unroll
  for (int m = 32; m > 0; m >>= 1) v += __shfl_xor(v, m, 64);
  return v;
}
// f32 -> bf16 round-to-nearest-even
__device__ __forceinline__ unsigned int f2bf(float f){
  unsigned int u = __builtin_bit_cast(unsigned int, f);
  u = u + 0x7fffu + ((u >> 16) & 1u);
  return (u >> 16);
}

// K0: sentence norms -> normalized bf16 rows
__global__ __launch_bounds__(256) void k_sent(const float* __restrict__ s,
                                              unsigned short* __restrict__ sb){
  int row  = blockIdx.x * 4 + (threadIdx.x >> 6);
  int lane = threadIdx.x & 63;
  const float* sr = s + (size_t)row * ND;
  float x[8]; float ss = 0.f;
#pragma unroll
  for (int e = 0; e < 8; e++){ x[e] = sr[lane + e*64]; ss += x[e]*x[e]; }
  ss = wred_sum(ss);
  float inv = 1.0f / fmaxf(sqrtf(ss), 1e-8f);
#pragma unroll
  for (int e = 0; e < 8; e++)
    sb[(size_t)row*ND + lane + e*64] = (unsigned short)f2bf(x[e]*inv);
}

// Fused: single video read. Plain C++ prefetch loads (compiler-managed vmcnt,
// position-pinned by sched_barrier), raw s_barrier + lgkmcnt(0) per K-step so
// in-flight loads survive barriers. Per-t norm + f32 diag as staging
// side-products; bf16 GEMM 64j x 512t; vinv on accumulator; fused softmax;
// coalesced store. Thread tid owns t-row tid and A-chunk (tid>>3, tid&7).
// launch_bounds (512,1): empirically arg2 scales the VGPR cap like blocks/CU
// ((512,2)->128, (512,4)->64 measured) — need 256 cap for the ~190-reg pipeline.
__global__ __launch_bounds__(512, 1) void k_fused(
    const unsigned short* __restrict__ sb,   // normalized sentences bf16
    const float* __restrict__ video,         // raw f32 video
    const float* __restrict__ sent,          // raw f32 sentences
    const int* __restrict__ lens,
    float* __restrict__ out0,
    float* __restrict__ diag){
  const int tid  = threadIdx.x;
  const int lane = tid & 63;
  const int w    = tid >> 6;
  const int wj   = w >> 2;      // 0..1
  const int wt   = w & 3;       // 0..3

  // XCD-grouped decode: 4 j-tile blocks of one b share (blockIdx & 7) -> same XCD L2
  const int D  = blockIdx.x;
  const int x8 = D & 7;
  const int r0 = D >> 3;
  const int s  = r0 & 3;        // j-tile 0..3
  const int b  = (r0 >> 2) * 8 + x8;
  const int jt = s * 64;

  __shared__ __align__(16) char pool[73728];  // As[2][64*32]bf16 8K + Bs[2][512*32]bf16 64K
  __shared__ float sRowS[ND];                 // 2 KB
  __shared__ float vinvS[NT];                 // 2 KB
  __shared__ float redM[64*4];
  __shared__ float redS[64*4];
  char* AsB = pool;
  char* BsB = pool + 8192;

  sRowS[tid] = sent[(size_t)b*ND + tid];

  const float* vrow = video + ((size_t)b*NT + tid) * ND;   // this thread's t-row
  const int ar = tid >> 3, ag = tid & 7;
  const unsigned short* arow = sb + (size_t)(jt + ar)*ND + ag*4;
  // A LDS byte offset (within buf), matches MFMA-read swizzle
  const int aoff = ar*64 + ((((ag>>1) ^ ((ar>>1)&3))) << 4) + ((ag&1) << 3);
  const int slw  = (tid >> 1) & 3;            // B write slot-swizzle key
  char* bp0 = BsB + tid*64;

  const int rl = lane & 15;
  const int gr = lane >> 4;
  const int goffA = ((gr ^ ((rl>>1)&3)) << 4);

  f32x4 acc[2][8] = {};
  float ssq = 0.f, dpp = 0.f;
  f32x4 vA[8], vB[8];
  u32x2 aA, aB;

#define LOADS(NB_, NA_, kk) { const float* _vp = vrow + (kk);                          \
  _Pragma("unroll") for (int i = 0; i < 8; i++)                                        \
    NB_[i] = *reinterpret_cast<const f32x4*>(_vp + i*4);                               \
  NA_ = *reinterpret_cast<const u32x2*>(arow + (kk)); }

#define CONSUME(I, CUR, ACUR) {                                                        \
  const int k0c = (I)*32;                                                              \
  float sq = 0.f, dq = 0.f;                                                            \
  _Pragma("unroll") for (int qq = 0; qq < 8; qq++){                                    \
    _Pragma("unroll") for (int jj = 0; jj < 4; jj++){                                  \
      float x = CUR[qq][jj]; sq += x*x; dq += x*sRowS[k0c + qq*4 + jj]; } }            \
  ssq += sq; dpp += dq;                                                                \
  char* bp = bp0 + ((I)&1)*32768;                                                      \
  _Pragma("unroll") for (int g = 0; g < 4; g++){                                       \
    u32x4 d;                                                                           \
    d[0] = f2bf(CUR[2*g  ][0]) | (f2bf(CUR[2*g  ][1]) << 16);                          \
    d[1] = f2bf(CUR[2*g  ][2]) | (f2bf(CUR[2*g  ][3]) << 16);                          \
    d[2] = f2bf(CUR[2*g+1][0]) | (f2bf(CUR[2*g+1][1]) << 16);                          \
    d[3] = f2bf(CUR[2*g+1][2]) | (f2bf(CUR[2*g+1][3]) << 16);                          \
    *reinterpret_cast<u32x4*>(bp + ((g ^ slw) << 4)) = d; }                            \
  *reinterpret_cast<u32x2*>(AsB + ((I)&1)*4096 + aoff) = ACUR; }

#define MFMA_PHASE(I) {                                                                \
  const int p = (I)&1;                                                                 \
  bf16x8 af0 = *reinterpret_cast<const bf16x8*>(AsB + p*4096 + (wj*32 +      rl)*64 + goffA); \
  bf16x8 af1 = *reinterpret_cast<const bf16x8*>(AsB + p*4096 + (wj*32 + 16 + rl)*64 + goffA); \
  _Pragma("unroll") for (int fj = 0; fj < 8; fj++){                                    \
    int t = wt*128 + fj*16 + rl;                                                       \
    bf16x8 bg = *reinterpret_cast<const bf16x8*>(BsB + p*32768 + t*64 + ((gr ^ ((t>>1)&3)) << 4)); \
    acc[0][fj] = __builtin_amdgcn_mfma_f32_16x16x32_bf16(af0, bg, acc[0][fj], 0, 0, 0); \
    acc[1][fj] = __builtin_amdgcn_mfma_f32_16x16x32_bf16(af1, bg, acc[1][fj], 0, 0, 0); } }

#define STEP(I, CUR, ACUR, NXT, ANXT) {                                                \
  if ((I) < 15) { LOADS(NXT, ANXT, ((I)+1)*32); }                                      \
  __builtin_amdgcn_sched_barrier(0);                                                   \
  CONSUME(I, CUR, ACUR);                                                               \
  asm volatile("s_waitcnt lgkmcnt(0)" ::: "memory");                                   \
  __builtin_amdgcn_sched_barrier(0);                                                   \
  __builtin_amdgcn_s_barrier();                                                        \
  __builtin_amdgcn_sched_barrier(0);                                                   \
  MFMA_PHASE(I);                                                                       \
  __builtin_amdgcn_sched_barrier(0); }

  // prologue: issue step-0 loads; make sRowS visible (raw barrier, no vm drain)
  LOADS(vA, aA, 0);
  asm volatile("s_waitcnt lgkmcnt(0)" ::: "memory");
  __builtin_amdgcn_sched_barrier(0);
  __builtin_amdgcn_s_barrier();
  __builtin_amdgcn_sched_barrier(0);

  STEP( 0, vA, aA, vB, aB);  STEP( 1, vB, aB, vA, aA);
  STEP( 2, vA, aA, vB, aB);  STEP( 3, vB, aB, vA, aA);
  STEP( 4, vA, aA, vB, aB);  STEP( 5, vB, aB, vA, aA);
  STEP( 6, vA, aA, vB, aB);  STEP( 7, vB, aB, vA, aA);
  STEP( 8, vA, aA, vB, aB);  STEP( 9, vB, aB, vA, aA);
  STEP(10, vA, aA, vB, aB);  STEP(11, vB, aB, vA, aA);
  STEP(12, vA, aA, vB, aB);  STEP(13, vB, aB, vA, aA);
  STEP(14, vA, aA, vB, aB);  STEP(15, vB, aB, vA, aA);

#undef STEP
#undef MFMA_PHASE
#undef CONSUME
#undef LOADS

  // ---- per-t norm (thread-local) + f32 diag (sentence-norm factor dropped:
  // positive per-b constant, argmax-invariant) ----
  {
    float inv = 1.0f / fmaxf(sqrtf(ssq), 1e-8f);
    vinvS[tid] = inv;
    if (s == 0) diag[(size_t)b*NT + tid] = dpp * inv;
  }
  __syncthreads();

  // ---- masked softmax over t (apply vinv to accumulator here) ----
  const int len = lens[b];
  const int q  = gr;
  const int tl = rl;
  const float NEGINF = -__builtin_inff();

  float mx[2][4];
#pragma unroll
  for (int fi = 0; fi < 2; fi++)
#pragma unroll
    for (int rr = 0; rr < 4; rr++) mx[fi][rr] = NEGINF;

#pragma unroll
  for (int fi = 0; fi < 2; fi++)
#pragma unroll
    for (int fj = 0; fj < 8; fj++){
      int t = wt*128 + fj*16 + tl;
      float vi = vinvS[t];
      bool ok = t < len;
#pragma unroll
      for (int rr = 0; rr < 4; rr++){
        float v = ok ? acc[fi][fj][rr]*vi : NEGINF;
        acc[fi][fj][rr] = v;
        mx[fi][rr] = fmaxf(mx[fi][rr], v);
      }
    }
#pragma unroll
  for (int fi = 0; fi < 2; fi++)
#pragma unroll
    for (int rr = 0; rr < 4; rr++)
#pragma unroll
      for (int msk = 1; msk <= 8; msk <<= 1)
        mx[fi][rr] = fmaxf(mx[fi][rr], __shfl_xor(mx[fi][rr], msk, 64));
  if (tl == 0){
#pragma unroll
    for (int fi = 0; fi < 2; fi++)
#pragma unroll
      for (int rr = 0; rr < 4; rr++)
        redM[(wj*32 + fi*16 + q*4 + rr)*4 + wt] = mx[fi][rr];
  }
  __syncthreads();

  float gmx[2][4], sum[2][4];
#pragma unroll
  for (int fi = 0; fi < 2; fi++)
#pragma unroll
    for (int rr = 0; rr < 4; rr++){
      int jl = wj*32 + fi*16 + q*4 + rr;
      gmx[fi][rr] = fmaxf(fmaxf(redM[jl*4+0], redM[jl*4+1]),
                          fmaxf(redM[jl*4+2], redM[jl*4+3]));
      sum[fi][rr] = 0.f;
    }
#pragma unroll
  for (int fi = 0; fi < 2; fi++)
#pragma unroll
    for (int fj = 0; fj < 8; fj++)
#pragma unroll
      for (int rr = 0; rr < 4; rr++){
        float e = __expf(acc[fi][fj][rr] - gmx[fi][rr]);  // exp(-inf)=0 masked
        acc[fi][fj][rr] = e;
        sum[fi][rr] += e;
      }
#pragma unroll
  for (int fi = 0; fi < 2; fi++)
#pragma unroll
    for (int rr = 0; rr < 4; rr++)
#pragma unroll
      for (int msk = 1; msk <= 8; msk <<= 1)
        sum[fi][rr] += __shfl_xor(sum[fi][rr], msk, 64);
  if (tl == 0){
#pragma unroll
    for (int fi = 0; fi < 2; fi++)
#pragma unroll
      for (int rr = 0; rr < 4; rr++)
        redS[(wj*32 + fi*16 + q*4 + rr)*4 + wt] = sum[fi][rr];
  }
  __syncthreads();

  float ivv[2][4];
#pragma unroll
  for (int fi = 0; fi < 2; fi++)
#pragma unroll
    for (int rr = 0; rr < 4; rr++){
      int jl = wj*32 + fi*16 + q*4 + rr;
      ivv[fi][rr] = 1.0f / ((redS[jl*4+0] + redS[jl*4+1]) + (redS[jl*4+2] + redS[jl*4+3]));
    }

  // ---- coalesced store via LDS transpose (reuse pool: 32 x 516 f32) ----
  float* pf = (float*)pool;
  const int r2 = tid >> 7;
  const int c4 = (tid & 127) * 4;
#pragma unroll
  for (int fi = 0; fi < 2; fi++){
    __syncthreads();
#pragma unroll
    for (int fj = 0; fj < 8; fj++){
      int t = wt*128 + fj*16 + tl;
#pragma unroll
      for (int rr = 0; rr < 4; rr++){
        int r = wj*16 + q*4 + rr;
        pf[r*516 + t] = acc[fi][fj][rr] * ivv[fi][rr];
      }
    }
    __syncthreads();
#pragma unroll
    for (int p = 0; p < 8; p++){
      int row = p*4 + r2;
      int gj  = jt + ((row >> 4) * 32) + fi*16 + (row & 15);
      f32x4 vv = *reinterpret_cast<const f32x4*>(pf + row*516 + c4);
      *reinterpret_cast<f32x4*>(out0 + ((size_t)b*NB + gj)*NT + c4) = vv;
    }
  }
}

// argmax over valid t of diag (first-index tie-break) + copy chosen frame row
__global__ __launch_bounds__(256) void k_argmax(const float* __restrict__ video,
                                                const int* __restrict__ lens,
                                                const float* __restrict__ diag,
                                                float* __restrict__ o1){
  int b = blockIdx.x;
  int tid = threadIdx.x;
  int len = lens[b];
  __shared__ float sv[256];
  __shared__ int   si[256];
  const float* dg = diag + (size_t)b * NT;
  float v1 = (tid       < len) ? dg[tid]       : -__builtin_inff();
  float v2 = (tid + 256 < len) ? dg[tid + 256] : -__builtin_inff();
  float bv; int bi;
  if (v2 > v1){ bv = v2; bi = tid + 256; } else { bv = v1; bi = tid; }
  sv[tid] = bv; si[tid] = bi;
  __syncthreads();
  for (int sN = 128; sN > 0; sN >>= 1){
    if (tid < sN){
      float ov = sv[tid+sN]; int oi = si[tid+sN];
      if (ov > sv[tid] || (ov == sv[tid] && oi < si[tid])){ sv[tid] = ov; si[tid] = oi; }
    }
    __syncthreads();
  }
  int best = si[0];
  const float* src = video + ((size_t)b * NT + best) * ND;
  o1[(size_t)b * ND + tid]       = src[tid];
  o1[(size_t)b * ND + tid + 256] = src[tid + 256];
}

extern "C" void kernel_launch(void* const* d_in, const int* in_sizes, int n_in,
                              void* d_out, int out_size, void* d_ws, size_t ws_size,
                              hipStream_t stream){
  const float* video = (const float*)d_in[0];
  const float* sent  = (const float*)d_in[1];
  const int*   lens  = (const int*)d_in[2];
  float* out0 = (float*)d_out;
  float* out1 = out0 + (size_t)NB*NB*NT;

  char* ws = (char*)d_ws;
  unsigned short* sb = (unsigned short*)ws;      // 262144 B
  float* diagw = (float*)(ws + 262144);          // 524288 B

  k_sent  <<<NB/4, 256, 0, stream>>>(sent, sb);
  k_fused <<<NB*4, 512, 0, stream>>>(sb, video, sent, lens, out0, diagw);
  k_argmax<<<NB,   256, 0, stream>>>(video, lens, diagw, out1);
}

// Round 9
// 225.846 us; speedup vs baseline: 4.1727x; 4.1727x over previous
//
#include <hip/hip_runtime.h>
#include <hip/hip_bf16.h>
#include <cstdint>

constexpr int NB = 256;   // batch
constexpr int NT = 512;   // frames
constexpr int ND = 512;   // dim

typedef __attribute__((ext_vector_type(8))) short bf16x8;
typedef __attribute__((ext_vector_type(4))) float f32x4;
typedef __attribute__((ext_vector_type(2))) unsigned int u32x2;

__device__ __forceinline__ float wred_sum(float v){
#pragma unroll
  for (int m = 32; m > 0; m >>= 1) v += __shfl_xor(v, m, 64);
  return v;
}
// f32 -> bf16 round-to-nearest-even
__device__ __forceinline__ unsigned int f2bf(float f){
  unsigned int u = __builtin_bit_cast(unsigned int, f);
  u = u + 0x7fffu + ((u >> 16) & 1u);
  return (u >> 16);
}
// async global->LDS, 16B per lane
__device__ __forceinline__ void gload_lds16(const void* g, void* l){
  __builtin_amdgcn_global_load_lds(
      (const __attribute__((address_space(1))) unsigned int*)g,
      (__attribute__((address_space(3))) unsigned int*)l, 16, 0, 0);
}

// K0: sentence norms -> normalized bf16 rows
__global__ __launch_bounds__(256) void k_sent(const float* __restrict__ s,
                                              unsigned short* __restrict__ sb){
  int row  = blockIdx.x * 4 + (threadIdx.x >> 6);
  int lane = threadIdx.x & 63;
  const float* sr = s + (size_t)row * ND;
  float x[8]; float ss = 0.f;
#pragma unroll
  for (int e = 0; e < 8; e++){ x[e] = sr[lane + e*64]; ss += x[e]*x[e]; }
  ss = wred_sum(ss);
  float inv = 1.0f / fmaxf(sqrtf(ss), 1e-8f);
#pragma unroll
  for (int e = 0; e < 8; e++)
    sb[(size_t)row*ND + lane + e*64] = (unsigned short)f2bf(x[e]*inv);
}

// Fused single-video-read kernel, ZERO register pipeline:
//   gload_lds f32 video -> LDS (async, counted vmcnt)
//   convert phase: LDS f32 -> ssq/dp partials + bf16 tile in LDS
//   MFMA phase every 2 half-steps (overlapped at loop top)
//   fused masked softmax + coalesced store.
// 64j x 512t per block, one b per block. ~70 VGPR demand -> no spills at the
// 128-reg cap for 512-thread blocks (measured r7/r8).
__global__ __launch_bounds__(512, 2) void k_fused(
    const unsigned short* __restrict__ sb,   // normalized sentences bf16
    const float* __restrict__ video,         // raw f32 video
    const float* __restrict__ sent,          // raw f32 sentences
    const int* __restrict__ lens,
    float* __restrict__ out0,
    float* __restrict__ diag){
  const int tid  = threadIdx.x;
  const int lane = tid & 63;
  const int w    = tid >> 6;
  const int wj   = w >> 2;      // 0..1
  const int wt   = w & 3;       // 0..3
  const int q    = tid & 3;     // convert chunk id

  // XCD-grouped decode: 4 j-tile blocks of one b share (blockIdx & 7)
  const int D  = blockIdx.x;
  const int x8 = D & 7;
  const int r0 = D >> 3;
  const int s  = r0 & 3;        // j-tile 0..3
  const int b  = (r0 >> 2) * 8 + x8;
  const int jt = s * 64;

  // pool: H f32 [2][512][16f32] @0 (64KB) | TB bf16 [2][512][4 slots*16B] @65536 (64KB)
  //       | TA bf16 [2][64][64B] @131072 (8KB)
  __shared__ __align__(16) char pool[139264];
  __shared__ float sRowS[ND];
  __shared__ float vinvS[NT];
  __shared__ float redM[64*4];
  __shared__ float redS[64*4];

  sRowS[tid] = sent[(size_t)b*ND + tid];

  // B-stage source: wave w stages rows w*64..w*64+63; instr i: rows i*16+(lane>>2)
  const float* vstage = video + ((size_t)(b*NT + w*64 + (lane>>2)))*ND + (lane&3)*4;
  // A-stage source (waves 0-3), r4/5-proven pre-swizzle
  const unsigned short* asrc =
      sb + (size_t)(jt + (w&3)*16 + (lane>>2))*ND + ((lane&3)^((lane>>3)&3))*8;

  const int rl = lane & 15;
  const int gr = lane >> 4;
  const int goffA = ((gr ^ ((rl>>1)&3)) << 4);

  f32x4 acc[2][8] = {};
  float pssq[4] = {}, pdp[4] = {};

#define STAGE_B(h) { const int hb=(h)&1;                                        \
  _Pragma("unroll") for (int i = 0; i < 4; i++)                                 \
    gload_lds16(vstage + (size_t)i*16*ND + (h)*16,                              \
                pool + hb*32768 + w*4096 + i*1024 + lane*16); }

#define STAGE_A(m) { if (w < 4)                                                 \
    gload_lds16(asrc + (m)*32, pool + 131072 + ((m)&1)*4096 + w*1024 + lane*16); }

// convert half-step h (PAR = h&1 compile-time): thread (4a+q) does chunk q of
// rows 4a+0..3: f32 LDS read -> ssq/dp partial -> bf16 b64 write (XOR-slotted)
#define CONVERT(h, PAR) {                                                       \
  f32x4 sc = *(const f32x4*)(sRowS + (h)*16 + q*4);                             \
  const char* hb_ = pool + (PAR)*32768 + (tid & ~3)*64 + q*16;                  \
  char* tb_ = pool + 65536 + (((h)>>1)&1)*32768;                                \
  const int db_ = 2*(PAR) + (q>>1);                                             \
  _Pragma("unroll") for (int i = 0; i < 4; i++){                                \
    f32x4 x = *(const f32x4*)(hb_ + i*64);                                      \
    pssq[i] += x[0]*x[0] + x[1]*x[1] + x[2]*x[2] + x[3]*x[3];                   \
    pdp[i]  += x[0]*sc[0] + x[1]*sc[1] + x[2]*sc[2] + x[3]*sc[3];               \
    u32x2 pk;                                                                   \
    pk[0] = f2bf(x[0]) | (f2bf(x[1]) << 16);                                    \
    pk[1] = f2bf(x[2]) | (f2bf(x[3]) << 16);                                    \
    const int row_ = (tid & ~3) + i;                                            \
    const int slot_ = db_ ^ ((row_ >> 1) & 3);                                  \
    *(u32x2*)(tb_ + row_*64 + slot_*16 + (q&1)*8) = pk; } }

#define MFMA_PHASE(mm) {                                                        \
  const int p_ = (mm)&1;                                                        \
  const char* Ab_ = pool + 131072 + p_*4096;                                    \
  const char* Bb_ = pool + 65536  + p_*32768;                                   \
  bf16x8 af0 = *(const bf16x8*)(Ab_ + (wj*32 +      rl)*64 + goffA);            \
  bf16x8 af1 = *(const bf16x8*)(Ab_ + (wj*32 + 16 + rl)*64 + goffA);            \
  _Pragma("unroll") for (int fj = 0; fj < 8; fj++){                             \
    int t_ = wt*128 + fj*16 + rl;                                               \
    bf16x8 bg = *(const bf16x8*)(Bb_ + t_*64 + ((gr ^ ((t_>>1)&3)) << 4));      \
    acc[0][fj] = __builtin_amdgcn_mfma_f32_16x16x32_bf16(af0, bg, acc[0][fj], 0,0,0); \
    acc[1][fj] = __builtin_amdgcn_mfma_f32_16x16x32_bf16(af1, bg, acc[1][fj], 0,0,0); } }

#define BARRIERS                                                                \
  __builtin_amdgcn_sched_barrier(0);                                            \
  __builtin_amdgcn_s_barrier();                                                 \
  __builtin_amdgcn_sched_barrier(0);

#define HALF_TAIL                                                               \
  __builtin_amdgcn_sched_barrier(0);                                            \
  asm volatile("s_waitcnt lgkmcnt(0)" ::: "memory");                            \
  BARRIERS

  // prologue: stage half 0 + A-tile 0; sRowS visible; full drain (once)
  STAGE_B(0);
  STAGE_A(0);
  __syncthreads();

  for (int m = 0; m < 16; ++m){
    if (m > 0){ MFMA_PHASE(m-1); }
    {  // h = 2m (even): issue B(h+1), wait stage(h), convert
      const int h = 2*m;
      STAGE_B(h+1);
      asm volatile("s_waitcnt vmcnt(4)" ::: "memory");
      BARRIERS
      CONVERT(h, 0)
      HALF_TAIL
    }
    if (m < 15){  // h = 2m+1 (odd): issue B(h+1) + A(m+1)
      const int h = 2*m+1;
      STAGE_B(h+1);
      STAGE_A(m+1);
      if (w < 4) asm volatile("s_waitcnt vmcnt(5)" ::: "memory");
      else       asm volatile("s_waitcnt vmcnt(4)" ::: "memory");
      BARRIERS
      CONVERT(h, 1)
      HALF_TAIL
    } else {      // h = 31: nothing left to issue
      asm volatile("s_waitcnt vmcnt(0)" ::: "memory");
      BARRIERS
      CONVERT(31, 1)
      HALF_TAIL
    }
  }
  MFMA_PHASE(15);

#undef STAGE_B
#undef STAGE_A
#undef CONVERT
#undef MFMA_PHASE

  // ---- reduce ssq/dp across the 4 q-lanes of each row-quad ----
#pragma unroll
  for (int i = 0; i < 4; i++){
#pragma unroll
    for (int msk = 1; msk <= 2; msk <<= 1){
      pssq[i] += __shfl_xor(pssq[i], msk, 64);
      pdp[i]  += __shfl_xor(pdp[i],  msk, 64);
    }
  }
  // thread owns row tid = 4a+q -> pick partial index q (static select)
  float myssq = (q==0) ? pssq[0] : (q==1) ? pssq[1] : (q==2) ? pssq[2] : pssq[3];
  float mydp  = (q==0) ? pdp[0]  : (q==1) ? pdp[1]  : (q==2) ? pdp[2]  : pdp[3];
  {
    float inv = 1.0f / fmaxf(sqrtf(myssq), 1e-8f);
    vinvS[tid] = inv;
    if (s == 0) diag[(size_t)b*NT + tid] = mydp * inv;  // sentence-norm factor
  }                                                     // dropped (argmax-invariant)
  __syncthreads();

  // ---- masked softmax over t (apply vinv to accumulator here) ----
  const int len = lens[b];
  const int tl = rl;
  const float NEGINF = -__builtin_inff();

  float mx[2][4];
#pragma unroll
  for (int fi = 0; fi < 2; fi++)
#pragma unroll
    for (int rr = 0; rr < 4; rr++) mx[fi][rr] = NEGINF;

#pragma unroll
  for (int fi = 0; fi < 2; fi++)
#pragma unroll
    for (int fj = 0; fj < 8; fj++){
      int t = wt*128 + fj*16 + tl;
      float vi = vinvS[t];
      bool ok = t < len;
#pragma unroll
      for (int rr = 0; rr < 4; rr++){
        float v = ok ? acc[fi][fj][rr]*vi : NEGINF;
        acc[fi][fj][rr] = v;
        mx[fi][rr] = fmaxf(mx[fi][rr], v);
      }
    }
#pragma unroll
  for (int fi = 0; fi < 2; fi++)
#pragma unroll
    for (int rr = 0; rr < 4; rr++)
#pragma unroll
      for (int msk = 1; msk <= 8; msk <<= 1)
        mx[fi][rr] = fmaxf(mx[fi][rr], __shfl_xor(mx[fi][rr], msk, 64));
  if (tl == 0){
#pragma unroll
    for (int fi = 0; fi < 2; fi++)
#pragma unroll
      for (int rr = 0; rr < 4; rr++)
        redM[(wj*32 + fi*16 + gr*4 + rr)*4 + wt] = mx[fi][rr];
  }
  __syncthreads();

  float gmx[2][4], sum[2][4];
#pragma unroll
  for (int fi = 0; fi < 2; fi++)
#pragma unroll
    for (int rr = 0; rr < 4; rr++){
      int jl = wj*32 + fi*16 + gr*4 + rr;
      gmx[fi][rr] = fmaxf(fmaxf(redM[jl*4+0], redM[jl*4+1]),
                          fmaxf(redM[jl*4+2], redM[jl*4+3]));
      sum[fi][rr] = 0.f;
    }
#pragma unroll
  for (int fi = 0; fi < 2; fi++)
#pragma unroll
    for (int fj = 0; fj < 8; fj++)
#pragma unroll
      for (int rr = 0; rr < 4; rr++){
        float e = __expf(acc[fi][fj][rr] - gmx[fi][rr]);  // exp(-inf)=0 masked
        acc[fi][fj][rr] = e;
        sum[fi][rr] += e;
      }
#pragma unroll
  for (int fi = 0; fi < 2; fi++)
#pragma unroll
    for (int rr = 0; rr < 4; rr++)
#pragma unroll
      for (int msk = 1; msk <= 8; msk <<= 1)
        sum[fi][rr] += __shfl_xor(sum[fi][rr], msk, 64);
  if (tl == 0){
#pragma unroll
    for (int fi = 0; fi < 2; fi++)
#pragma unroll
      for (int rr = 0; rr < 4; rr++)
        redS[(wj*32 + fi*16 + gr*4 + rr)*4 + wt] = sum[fi][rr];
  }
  __syncthreads();

  float ivv[2][4];
#pragma unroll
  for (int fi = 0; fi < 2; fi++)
#pragma unroll
    for (int rr = 0; rr < 4; rr++){
      int jl = wj*32 + fi*16 + gr*4 + rr;
      ivv[fi][rr] = 1.0f / ((redS[jl*4+0] + redS[jl*4+1]) + (redS[jl*4+2] + redS[jl*4+3]));
    }

  // ---- coalesced store via LDS transpose (reuse pool: 32 x 516 f32) ----
  float* pf = (float*)pool;
  const int r2 = tid >> 7;
  const int c4 = (tid & 127) * 4;
#pragma unroll
  for (int fi = 0; fi < 2; fi++){
    __syncthreads();
#pragma unroll
    for (int fj = 0; fj < 8; fj++){
      int t = wt*128 + fj*16 + tl;
#pragma unroll
      for (int rr = 0; rr < 4; rr++){
        int r = wj*16 + gr*4 + rr;
        pf[r*516 + t] = acc[fi][fj][rr] * ivv[fi][rr];
      }
    }
    __syncthreads();
#pragma unroll
    for (int p = 0; p < 8; p++){
      int row = p*4 + r2;
      int gj  = jt + ((row >> 4) * 32) + fi*16 + (row & 15);
      f32x4 vv = *reinterpret_cast<const f32x4*>(pf + row*516 + c4);
      *reinterpret_cast<f32x4*>(out0 + ((size_t)b*NB + gj)*NT + c4) = vv;
    }
  }
}

// argmax over valid t of diag (first-index tie-break) + copy chosen frame row
__global__ __launch_bounds__(256) void k_argmax(const float* __restrict__ video,
                                                const int* __restrict__ lens,
                                                const float* __restrict__ diag,
                                                float* __restrict__ o1){
  int b = blockIdx.x;
  int tid = threadIdx.x;
  int len = lens[b];
  __shared__ float sv[256];
  __shared__ int   si[256];
  const float* dg = diag + (size_t)b * NT;
  float v1 = (tid       < len) ? dg[tid]       : -__builtin_inff();
  float v2 = (tid + 256 < len) ? dg[tid + 256] : -__builtin_inff();
  float bv; int bi;
  if (v2 > v1){ bv = v2; bi = tid + 256; } else { bv = v1; bi = tid; }
  sv[tid] = bv; si[tid] = bi;
  __syncthreads();
  for (int sN = 128; sN > 0; sN >>= 1){
    if (tid < sN){
      float ov = sv[tid+sN]; int oi = si[tid+sN];
      if (ov > sv[tid] || (ov == sv[tid] && oi < si[tid])){ sv[tid] = ov; si[tid] = oi; }
    }
    __syncthreads();
  }
  int best = si[0];
  const float* src = video + ((size_t)b * NT + best) * ND;
  o1[(size_t)b * ND + tid]       = src[tid];
  o1[(size_t)b * ND + tid + 256] = src[tid + 256];
}

extern "C" void kernel_launch(void* const* d_in, const int* in_sizes, int n_in,
                              void* d_out, int out_size, void* d_ws, size_t ws_size,
                              hipStream_t stream){
  const float* video = (const float*)d_in[0];
  const float* sent  = (const float*)d_in[1];
  const int*   lens  = (const int*)d_in[2];
  float* out0 = (float*)d_out;
  float* out1 = out0 + (size_t)NB*NB*NT;

  char* ws = (char*)d_ws;
  unsigned short* sb = (unsigned short*)ws;      // 262144 B
  float* diagw = (float*)(ws + 262144);          // 524288 B

  k_sent  <<<NB/4, 256, 0, stream>>>(sent, sb);
  k_fused <<<NB*4, 512, 0, stream>>>(sb, video, sent, lens, out0, diagw);
  k_argmax<<<NB,   256, 0, stream>>>(video, lens, diagw, out1);
}